// Round 1
// 800.226 us; speedup vs baseline: 1.0684x; 1.0684x over previous
//
#include <hip/hip_runtime.h>
#include <math.h>

typedef _Float16 f16;
typedef _Float16 f16x8 __attribute__((ext_vector_type(8)));
typedef float f32x4 __attribute__((ext_vector_type(4)));

#define NSTEP 128
#define FEAT  127
#define BLK_B 16
#define NBLOCK 256
#define NTHREADS 512

__device__ __forceinline__ float sigf(float x) { return 1.0f / (1.0f + __expf(-x)); }
__device__ __forceinline__ float tanh_(float x) { return 1.0f - 2.0f / (1.0f + __expf(2.0f * x)); }

// Barrier that only guarantees LDS visibility: no vmcnt(0) drain, so global
// stores (h0g/out) and prefetch loads stay in flight across steps.
__device__ __forceinline__ void sync_lds() {
    asm volatile("s_waitcnt lgkmcnt(0)" ::: "memory");
    __builtin_amdgcn_s_barrier();
    asm volatile("" ::: "memory");
}

#define PIN(v) asm volatile("" : "+v"(v))

// f16 MFMA B-fragments in d_ws. Segments sel: 0=w_ih0 1=w_hh0 2=w_ih1 3=w_hh1,
// each 65536 halfs. Fragment (sel,wave,gate,ks,lane) = f16x8 at
//   sel*8192 + ((wave*4+gate)*4+ks)*64 + lane
// holding W[n][k], n = gate*128 + wave*16 + (lane&15), k = ks*32 + (lane>>4)*8 + j.
__global__ void prep_weights(const float* __restrict__ w_ih0,
                             const float* __restrict__ w_hh0,
                             const float* __restrict__ w_ih1,
                             const float* __restrict__ w_hh1,
                             f16* __restrict__ ws16)
{
    int idx = blockIdx.x * blockDim.x + threadIdx.x;  // 0 .. 262143
    int j    = idx & 7;
    int lane = (idx >> 3) & 63;
    int ks   = (idx >> 9) & 3;
    int gate = (idx >> 11) & 3;
    int wave = (idx >> 13) & 7;
    int sel  = (idx >> 16) & 3;
    int n = gate * 128 + wave * 16 + (lane & 15);
    int k = ks * 32 + (lane >> 4) * 8 + j;
    const float* W = (sel == 0) ? w_ih0 : (sel == 1) ? w_hh0 : (sel == 2) ? w_ih1 : w_hh1;
    ws16[idx] = (f16)W[n * 128 + k];
}

// ---------------- Phase 1: layer 0 only, h0 sequence -> global (f16) ----------
__global__ __launch_bounds__(NTHREADS, 2) void lstm_l0(
    const float* __restrict__ nf,   const float* __restrict__ tgt,
    const float* __restrict__ b_ih0, const float* __restrict__ b_hh0,
    const f16* __restrict__ wfrag,  f16* __restrict__ h0g)
{
    __shared__ __align__(16) f16 xs[2][16][152];
    __shared__ __align__(16) f16 h0s[2][16][152];

    const int tid  = threadIdx.x;
    const int wave = tid >> 6;
    const int lane = tid & 63;
    const int col  = lane & 15;
    const int quad = lane >> 4;
    const int b0   = blockIdx.x * BLK_B;
    const int u    = wave * 16 + col;

    for (int i = tid; i < 2 * 16 * 152; i += NTHREADS)
        (&h0s[0][0][0])[i] = (f16)0.0f;

    float bias0[4];
#pragma unroll
    for (int g = 0; g < 4; ++g)
        bias0[g] = b_ih0[g * 128 + u] + b_hh0[g * 128 + u];

    const f16x8* wf = (const f16x8*)wfrag;

    // persistent fragments: 32 x f16x8 = 128 VGPRs, pinned so they cannot be re-sunk
    f16x8 wih0[4][4], whh0[4][4];
#pragma unroll
    for (int g = 0; g < 4; ++g)
#pragma unroll
        for (int ks = 0; ks < 4; ++ks) {
            const int fi = ((wave * 4 + g) * 4 + ks) * 64 + lane;
            wih0[g][ks] = wf[0 * 8192 + fi];
            whh0[g][ks] = wf[1 * 8192 + fi];
            PIN(wih0[g][ks]);
            PIN(whh0[g][ks]);
        }

    // streaming prefetch pointers for x(t+1): k<FEAT -> nf row, k==127 -> tgt
    const float* px[2][2];
    int pxs[2][2];
#pragma unroll
    for (int rr = 0; rr < 2; ++rr) {
        const long rowg = b0 + wave * 2 + rr;
#pragma unroll
        for (int h = 0; h < 2; ++h) {
            const int k = lane + 64 * h;
            if (k < FEAT) { px[rr][h] = nf + (rowg * NSTEP + 1) * FEAT + k; pxs[rr][h] = FEAT; }
            else          { px[rr][h] = tgt + rowg * NSTEP;                 pxs[rr][h] = 1; }
        }
    }

    // stepping h0g store pointer: lane owns rows quad*4+r, unit u; +128 halfs per step
    f16* hp = h0g + (long)(b0 + quad * 4) * NSTEP * 128 + u;

    f32x4 c0 = {0.f, 0.f, 0.f, 0.f};

    // stage x(0)
#pragma unroll
    for (int rr = 0; rr < 2; ++rr) {
        const int row = wave * 2 + rr;
        const long gbt = (long)(b0 + row) * NSTEP;
#pragma unroll
        for (int h = 0; h < 2; ++h) {
            const int k = lane + 64 * h;
            xs[0][row][k] = (f16)((k < FEAT) ? nf[gbt * FEAT + k] : 0.0f);
        }
    }
    sync_lds();

    for (int t = 0; t < NSTEP; ++t) {
        const int pa = t & 1, wb = pa ^ 1;

        // issue x(t+1) prefetch loads (consumed just before the barrier)
        float xnv[2][2] = {{0.f, 0.f}, {0.f, 0.f}};
        if (t + 1 < NSTEP) {
#pragma unroll
            for (int rr = 0; rr < 2; ++rr)
#pragma unroll
                for (int h = 0; h < 2; ++h)
                    xnv[rr][h] = *px[rr][h];
        }

        // preload ALL A-fragments up front: overlaps the 8 ds_read_b128 latencies
        f16x8 ax[4], ah[4];
#pragma unroll
        for (int ks = 0; ks < 4; ++ks) {
            ax[ks] = *(const f16x8*)&xs[pa][col][ks * 32 + quad * 8];
            ah[ks] = *(const f16x8*)&h0s[pa][col][ks * 32 + quad * 8];
        }

        // split accumulators: x-chain and h-chain independent, depth 4 each
        f32x4 accx[4], acch[4];
#pragma unroll
        for (int g = 0; g < 4; ++g) {
            accx[g] = (f32x4){bias0[g], bias0[g], bias0[g], bias0[g]};
            acch[g] = (f32x4){0.f, 0.f, 0.f, 0.f};
        }
#pragma unroll
        for (int ks = 0; ks < 4; ++ks)
#pragma unroll
            for (int g = 0; g < 4; ++g)
                accx[g] = __builtin_amdgcn_mfma_f32_16x16x32_f16(ax[ks], wih0[g][ks], accx[g], 0, 0, 0);
#pragma unroll
        for (int ks = 0; ks < 4; ++ks)
#pragma unroll
            for (int g = 0; g < 4; ++g)
                acch[g] = __builtin_amdgcn_mfma_f32_16x16x32_f16(ah[ks], whh0[g][ks], acch[g], 0, 0, 0);

        float h0n[4];
#pragma unroll
        for (int r = 0; r < 4; ++r) {
            const float ig = sigf(accx[0][r] + acch[0][r]);
            const float fg = sigf(accx[1][r] + acch[1][r]);
            const float gg = tanh_(accx[2][r] + acch[2][r]);
            const float og = sigf(accx[3][r] + acch[3][r]);
            const float cn = fg * c0[r] + ig * gg;
            c0[r] = cn;
            h0n[r] = og * tanh_(cn);
        }
#pragma unroll
        for (int r = 0; r < 4; ++r) {
            h0s[wb][quad * 4 + r][u] = (f16)h0n[r];
            hp[r * (NSTEP * 128)] = (f16)h0n[r];   // store left in flight across barrier
        }
        hp += 128;

        // stage prefetched x(t+1) (vmcnt wait lands here, as late as possible)
        if (t + 1 < NSTEP) {
#pragma unroll
            for (int rr = 0; rr < 2; ++rr)
#pragma unroll
                for (int h = 0; h < 2; ++h) {
                    xs[wb][wave * 2 + rr][lane + 64 * h] = (f16)xnv[rr][h];
                    px[rr][h] += pxs[rr][h];
                }
        }
        sync_lds();
    }
}

// ---------------- Phase 2: layer 1 + output ----------------------------------
__global__ __launch_bounds__(NTHREADS, 2) void lstm_l1(
    const f16* __restrict__ h0g,
    const float* __restrict__ b_ih1, const float* __restrict__ b_hh1,
    const float* __restrict__ w_out, const float* __restrict__ b_out,
    const f16* __restrict__ wfrag,  float* __restrict__ out)
{
    __shared__ __align__(16) f16 hx[2][16][152];
    __shared__ __align__(16) f16 h1s[2][16][152];
    __shared__ float outp[2][8][16];

    const int tid  = threadIdx.x;
    const int wave = tid >> 6;
    const int lane = tid & 63;
    const int col  = lane & 15;
    const int quad = lane >> 4;
    const int b0   = blockIdx.x * BLK_B;
    const int u    = wave * 16 + col;

    for (int i = tid; i < 2 * 16 * 152; i += NTHREADS)
        (&h1s[0][0][0])[i] = (f16)0.0f;

    float bias1[4];
#pragma unroll
    for (int g = 0; g < 4; ++g)
        bias1[g] = b_ih1[g * 128 + u] + b_hh1[g * 128 + u];
    const float wo_u = w_out[u];
    const float bout = b_out[0];

    const f16x8* wf = (const f16x8*)wfrag;

    f16x8 wih1[4][4], whh1[4][4];
#pragma unroll
    for (int g = 0; g < 4; ++g)
#pragma unroll
        for (int ks = 0; ks < 4; ++ks) {
            const int fi = ((wave * 4 + g) * 4 + ks) * 64 + lane;
            wih1[g][ks] = wf[2 * 8192 + fi];
            whh1[g][ks] = wf[3 * 8192 + fi];
            PIN(wih1[g][ks]);
            PIN(whh1[g][ks]);
        }

    // stepping h0 prefetch pointers (dword = 2 halfs per lane per row)
    const unsigned* rp[2];
#pragma unroll
    for (int rr = 0; rr < 2; ++rr) {
        const int row = wave * 2 + rr;
        rp[rr] = (const unsigned*)(h0g + ((long)(b0 + row) * NSTEP + 1) * 128) + lane;
    }

    f32x4 c1 = {0.f, 0.f, 0.f, 0.f};

    // stage h0(0)
#pragma unroll
    for (int rr = 0; rr < 2; ++rr) {
        const int row = wave * 2 + rr;
        const unsigned* sp = (const unsigned*)(h0g + ((long)(b0 + row) * NSTEP) * 128);
        *(unsigned*)&hx[0][row][lane * 2] = sp[lane];
    }
    sync_lds();

    for (int t = 0; t < NSTEP; ++t) {
        const int pa = t & 1, wb = pa ^ 1;

        // prefetch h0(t+1)
        unsigned hnv[2] = {0u, 0u};
        if (t + 1 < NSTEP) {
#pragma unroll
            for (int rr = 0; rr < 2; ++rr)
                hnv[rr] = rp[rr][0];
        }

        f16x8 axv[4], ahv[4];
#pragma unroll
        for (int ks = 0; ks < 4; ++ks) {
            axv[ks] = *(const f16x8*)&hx[pa][col][ks * 32 + quad * 8];
            ahv[ks] = *(const f16x8*)&h1s[pa][col][ks * 32 + quad * 8];
        }

        f32x4 accx[4], acch[4];
#pragma unroll
        for (int g = 0; g < 4; ++g) {
            accx[g] = (f32x4){bias1[g], bias1[g], bias1[g], bias1[g]};
            acch[g] = (f32x4){0.f, 0.f, 0.f, 0.f};
        }
#pragma unroll
        for (int ks = 0; ks < 4; ++ks)
#pragma unroll
            for (int g = 0; g < 4; ++g)
                accx[g] = __builtin_amdgcn_mfma_f32_16x16x32_f16(axv[ks], wih1[g][ks], accx[g], 0, 0, 0);
#pragma unroll
        for (int ks = 0; ks < 4; ++ks)
#pragma unroll
            for (int g = 0; g < 4; ++g)
                acch[g] = __builtin_amdgcn_mfma_f32_16x16x32_f16(ahv[ks], whh1[g][ks], acch[g], 0, 0, 0);

        float h1n[4];
#pragma unroll
        for (int r = 0; r < 4; ++r) {
            const float ig = sigf(accx[0][r] + acch[0][r]);
            const float fg = sigf(accx[1][r] + acch[1][r]);
            const float gg = tanh_(accx[2][r] + acch[2][r]);
            const float og = sigf(accx[3][r] + acch[3][r]);
            const float cn = fg * c1[r] + ig * gg;
            c1[r] = cn;
            h1n[r] = og * tanh_(cn);
        }
#pragma unroll
        for (int r = 0; r < 4; ++r)
            h1s[wb][quad * 4 + r][u] = (f16)h1n[r];

        // output partial (DS-pipe shuffles overlap the in-flight hnv loads)
        float ps[4];
#pragma unroll
        for (int r = 0; r < 4; ++r) ps[r] = h1n[r] * wo_u;
#pragma unroll
        for (int m = 1; m < 16; m <<= 1) {
#pragma unroll
            for (int r = 0; r < 4; ++r) ps[r] += __shfl_xor(ps[r], m, 64);
        }
        if (col == 0) {
#pragma unroll
            for (int r = 0; r < 4; ++r) outp[pa][wave][quad * 4 + r] = ps[r];
        }

        // stage prefetched h0(t+1) (vmcnt wait lands here)
        if (t + 1 < NSTEP) {
#pragma unroll
            for (int rr = 0; rr < 2; ++rr) {
                *(unsigned*)&hx[wb][wave * 2 + rr][lane * 2] = hnv[rr];
                rp[rr] += 64;
            }
        }

        sync_lds();

        if (tid < 16) {
            float s = bout;
#pragma unroll
            for (int w = 0; w < 8; ++w) s += outp[pa][w][tid];
            out[(long)(b0 + tid) * NSTEP + t] = sigf(s);
        }
    }
}

// ---------------- Fallback (R2 single-kernel, known-passing) ------------------
__global__ __launch_bounds__(NTHREADS, 2) void lstm_fb(
    const float* __restrict__ nf,   const float* __restrict__ tgt,
    const float* __restrict__ b_ih0, const float* __restrict__ b_hh0,
    const float* __restrict__ b_ih1, const float* __restrict__ b_hh1,
    const float* __restrict__ w_out, const float* __restrict__ b_out,
    const f16* __restrict__ wfrag,  float* __restrict__ out)
{
    __shared__ f16 xs[2][16][152];
    __shared__ f16 h0s[2][16][152];
    __shared__ f16 h1s[2][16][152];
    __shared__ float outp[8][16];

    const int tid  = threadIdx.x;
    const int wave = tid >> 6;
    const int lane = tid & 63;
    const int col  = lane & 15;
    const int quad = lane >> 4;
    const int b0   = blockIdx.x * BLK_B;
    const int u    = wave * 16 + col;

    for (int i = tid; i < 2 * 16 * 152; i += NTHREADS) {
        (&h0s[0][0][0])[i] = (f16)0.0f;
        (&h1s[0][0][0])[i] = (f16)0.0f;
    }
    float bias0[4], bias1[4];
#pragma unroll
    for (int g = 0; g < 4; ++g) {
        bias0[g] = b_ih0[g * 128 + u] + b_hh0[g * 128 + u];
        bias1[g] = b_ih1[g * 128 + u] + b_hh1[g * 128 + u];
    }
    const float wo_u = w_out[u];
    const float bout = b_out[0];
    const f16x8* wf = (const f16x8*)wfrag;

    f32x4 c0 = {0.f, 0.f, 0.f, 0.f};
    f32x4 c1 = {0.f, 0.f, 0.f, 0.f};

#pragma unroll
    for (int rr = 0; rr < 2; ++rr) {
        const int row = wave * 2 + rr;
        const long gbt = (long)(b0 + row) * NSTEP;
#pragma unroll
        for (int h = 0; h < 2; ++h) {
            const int k = lane + 64 * h;
            xs[0][row][k] = (f16)((k < FEAT) ? nf[gbt * FEAT + k] : 0.0f);
        }
    }
    __syncthreads();

    for (int t = 0; t < NSTEP; ++t) {
        const int pa = t & 1, wb = pa ^ 1;
        float xnv[2][2];
#pragma unroll
        for (int rr = 0; rr < 2; ++rr) {
            const int row = wave * 2 + rr;
#pragma unroll
            for (int h = 0; h < 2; ++h) {
                const int k = lane + 64 * h;
                float v = 0.0f;
                if (t + 1 < NSTEP) {
                    const long gbt = (long)(b0 + row) * NSTEP + (t + 1);
                    v = (k < FEAT) ? nf[gbt * FEAT + k] : tgt[(long)(b0 + row) * NSTEP + t];
                }
                xnv[rr][h] = v;
            }
        }
        f32x4 acc[4];
#pragma unroll
        for (int g = 0; g < 4; ++g) acc[g] = (f32x4){bias0[g], bias0[g], bias0[g], bias0[g]};
#pragma unroll
        for (int ks = 0; ks < 4; ++ks) {
            f16x8 a = *(const f16x8*)&xs[pa][col][ks * 32 + quad * 8];
#pragma unroll
            for (int g = 0; g < 4; ++g) {
                f16x8 b = wf[((wave * 4 + g) * 4 + ks) * 64 + lane];
                acc[g] = __builtin_amdgcn_mfma_f32_16x16x32_f16(a, b, acc[g], 0, 0, 0);
            }
        }
#pragma unroll
        for (int ks = 0; ks < 4; ++ks) {
            f16x8 a = *(const f16x8*)&h0s[pa][col][ks * 32 + quad * 8];
#pragma unroll
            for (int g = 0; g < 4; ++g) {
                f16x8 b = wf[1 * 8192 + ((wave * 4 + g) * 4 + ks) * 64 + lane];
                acc[g] = __builtin_amdgcn_mfma_f32_16x16x32_f16(a, b, acc[g], 0, 0, 0);
            }
        }
        float h0n[4];
#pragma unroll
        for (int r = 0; r < 4; ++r) {
            const float ig = sigf(acc[0][r]);
            const float fg = sigf(acc[1][r]);
            const float gg = tanh_(acc[2][r]);
            const float og = sigf(acc[3][r]);
            const float cn = fg * c0[r] + ig * gg;
            c0[r] = cn;
            h0n[r] = og * tanh_(cn);
        }
#pragma unroll
        for (int r = 0; r < 4; ++r) h0s[wb][quad * 4 + r][u] = (f16)h0n[r];
        __syncthreads();

#pragma unroll
        for (int g = 0; g < 4; ++g) acc[g] = (f32x4){bias1[g], bias1[g], bias1[g], bias1[g]};
#pragma unroll
        for (int ks = 0; ks < 4; ++ks) {
            f16x8 a = *(const f16x8*)&h0s[wb][col][ks * 32 + quad * 8];
#pragma unroll
            for (int g = 0; g < 4; ++g) {
                f16x8 b = wf[2 * 8192 + ((wave * 4 + g) * 4 + ks) * 64 + lane];
                acc[g] = __builtin_amdgcn_mfma_f32_16x16x32_f16(a, b, acc[g], 0, 0, 0);
            }
        }
#pragma unroll
        for (int ks = 0; ks < 4; ++ks) {
            f16x8 a = *(const f16x8*)&h1s[pa][col][ks * 32 + quad * 8];
#pragma unroll
            for (int g = 0; g < 4; ++g) {
                f16x8 b = wf[3 * 8192 + ((wave * 4 + g) * 4 + ks) * 64 + lane];
                acc[g] = __builtin_amdgcn_mfma_f32_16x16x32_f16(a, b, acc[g], 0, 0, 0);
            }
        }
        float h1n[4];
#pragma unroll
        for (int r = 0; r < 4; ++r) {
            const float ig = sigf(acc[0][r]);
            const float fg = sigf(acc[1][r]);
            const float gg = tanh_(acc[2][r]);
            const float og = sigf(acc[3][r]);
            const float cn = fg * c1[r] + ig * gg;
            c1[r] = cn;
            h1n[r] = og * tanh_(cn);
        }
#pragma unroll
        for (int r = 0; r < 4; ++r) h1s[wb][quad * 4 + r][u] = (f16)h1n[r];
#pragma unroll
        for (int rr = 0; rr < 2; ++rr) {
            const int row = wave * 2 + rr;
#pragma unroll
            for (int h = 0; h < 2; ++h) xs[wb][row][lane + 64 * h] = (f16)xnv[rr][h];
        }
        float ps[4];
#pragma unroll
        for (int r = 0; r < 4; ++r) ps[r] = h1n[r] * wo_u;
#pragma unroll
        for (int m = 1; m < 16; m <<= 1) {
#pragma unroll
            for (int r = 0; r < 4; ++r) ps[r] += __shfl_xor(ps[r], m, 64);
        }
        if (col == 0) {
#pragma unroll
            for (int r = 0; r < 4; ++r) outp[wave][quad * 4 + r] = ps[r];
        }
        __syncthreads();
        if (tid < 16) {
            float s = bout;
#pragma unroll
            for (int w = 0; w < 8; ++w) s += outp[w][tid];
            out[(long)(b0 + tid) * NSTEP + t] = sigf(s);
        }
    }
}

extern "C" void kernel_launch(void* const* d_in, const int* in_sizes, int n_in,
                              void* d_out, int out_size, void* d_ws, size_t ws_size,
                              hipStream_t stream)
{
    const float* nf    = (const float*)d_in[0];
    const float* tgt   = (const float*)d_in[1];
    const float* w_ih0 = (const float*)d_in[2];
    const float* w_hh0 = (const float*)d_in[3];
    const float* b_ih0 = (const float*)d_in[4];
    const float* b_hh0 = (const float*)d_in[5];
    const float* w_ih1 = (const float*)d_in[6];
    const float* w_hh1 = (const float*)d_in[7];
    const float* b_ih1 = (const float*)d_in[8];
    const float* b_hh1 = (const float*)d_in[9];
    const float* w_out = (const float*)d_in[10];
    const float* b_out = (const float*)d_in[11];

    f16*   ws16 = (f16*)d_ws;                    // 512 KB fragments
    float* out  = (float*)d_out;

    prep_weights<<<1024, 256, 0, stream>>>(w_ih0, w_hh0, w_ih1, w_hh1, ws16);

    const size_t need = 512 * 1024 + (size_t)4096 * 128 * 128 * 2;  // frags + h0seq (f16)
    if (ws_size >= need) {
        f16* h0g = ws16 + 4 * 65536;             // after the 512 KB fragment table
        lstm_l0<<<NBLOCK, NTHREADS, 0, stream>>>(nf, tgt, b_ih0, b_hh0, ws16, h0g);
        lstm_l1<<<NBLOCK, NTHREADS, 0, stream>>>(h0g, b_ih1, b_hh1, w_out, b_out, ws16, out);
    } else {
        lstm_fb<<<NBLOCK, NTHREADS, 0, stream>>>(nf, tgt, b_ih0, b_hh0, b_ih1, b_hh1,
                                                 w_out, b_out, ws16, out);
    }
}

// Round 4
// 789.945 us; speedup vs baseline: 1.0823x; 1.0130x over previous
//
#include <hip/hip_runtime.h>
#include <math.h>

typedef _Float16 f16;
typedef _Float16 f16x8 __attribute__((ext_vector_type(8)));
typedef float f32x4 __attribute__((ext_vector_type(4)));

#define NSTEP 128
#define FEAT  127
#define BLK_B 16
#define NBLOCK 256
#define NTHREADS 512

__device__ __forceinline__ float sigf(float x) { return 1.0f / (1.0f + __expf(-x)); }
__device__ __forceinline__ float tanh_(float x) { return 1.0f - 2.0f / (1.0f + __expf(2.0f * x)); }

// Barrier that only guarantees LDS visibility: no vmcnt(0) drain, so global
// stores (h0g/out) and prefetch loads stay in flight across steps.
__device__ __forceinline__ void sync_lds() {
    asm volatile("s_waitcnt lgkmcnt(0)" ::: "memory");
    __builtin_amdgcn_s_barrier();
    asm volatile("" ::: "memory");
}

#define PIN(v) asm volatile("" : "+v"(v))

// Load one MFMA B-fragment directly from the f32 weight matrix.
// Lane holds W[n][k..k+7] as f16x8 (same RTE conversion as the old prep kernel).
__device__ __forceinline__ f16x8 load_wfrag(const float* __restrict__ W, int n, int k) {
    const float* p = W + n * 128 + k;
    f16x8 r;
#pragma unroll
    for (int j = 0; j < 8; ++j) r[j] = (f16)p[j];
    return r;
}

// Sum over the 16-lane DPP row (our `col` dimension) via row_shr cascade.
// DPP ctrl must be a literal constant -> hand-unrolled. bound_ctrl=1 reads 0
// for shifted-in lanes. Result valid at col==15 of each 16-lane row.
__device__ __forceinline__ float row16_sum(float v) {
    int t;
    t = __builtin_amdgcn_update_dpp(0, __float_as_int(v), 0x118, 0xf, 0xf, true); // row_shr:8
    v += __int_as_float(t);
    t = __builtin_amdgcn_update_dpp(0, __float_as_int(v), 0x114, 0xf, 0xf, true); // row_shr:4
    v += __int_as_float(t);
    t = __builtin_amdgcn_update_dpp(0, __float_as_int(v), 0x112, 0xf, 0xf, true); // row_shr:2
    v += __int_as_float(t);
    t = __builtin_amdgcn_update_dpp(0, __float_as_int(v), 0x111, 0xf, 0xf, true); // row_shr:1
    v += __int_as_float(t);
    return v;
}

// ---------------- Fused kernel: layer 0 then layer 1, block-local ------------
__global__ __launch_bounds__(NTHREADS, 2) void lstm_fused(
    const float* __restrict__ nf,    const float* __restrict__ tgt,
    const float* __restrict__ w_ih0, const float* __restrict__ w_hh0,
    const float* __restrict__ b_ih0, const float* __restrict__ b_hh0,
    const float* __restrict__ w_ih1, const float* __restrict__ w_hh1,
    const float* __restrict__ b_ih1, const float* __restrict__ b_hh1,
    const float* __restrict__ w_out, const float* __restrict__ b_out,
    f16* __restrict__ h0g, float* __restrict__ out)
{
    __shared__ __align__(16) f16 bufA[2][16][152];   // phase0: xs   phase1: h1s
    __shared__ __align__(16) f16 bufB[2][16][152];   // phase0: h0s
    __shared__ float outp[2][8][16];

    const int tid  = threadIdx.x;
    const int wave = tid >> 6;
    const int lane = tid & 63;
    const int col  = lane & 15;
    const int quad = lane >> 4;
    const int b0   = blockIdx.x * BLK_B;
    const int u    = wave * 16 + col;
    const f32x4 zz = {0.f, 0.f, 0.f, 0.f};

    // ================= phase 0: layer 0, h0 sequence -> h0g ==================
    {
        for (int i = tid; i < 2 * 16 * 152; i += NTHREADS)
            (&bufB[0][0][0])[i] = (f16)0.0f;

        f32x4 bv0[4];
#pragma unroll
        for (int g = 0; g < 4; ++g) {
            const float b = b_ih0[g * 128 + u] + b_hh0[g * 128 + u];
            bv0[g] = (f32x4){b, b, b, b};
        }

        // weight fragments straight from global f32 (no prep kernel)
        f16x8 wih0[4][4], whh0[4][4];
#pragma unroll
        for (int g = 0; g < 4; ++g)
#pragma unroll
            for (int ks = 0; ks < 4; ++ks) {
                wih0[g][ks] = load_wfrag(w_ih0, g * 128 + u, ks * 32 + quad * 8);
                whh0[g][ks] = load_wfrag(w_hh0, g * 128 + u, ks * 32 + quad * 8);
                PIN(wih0[g][ks]);
                PIN(whh0[g][ks]);
            }

        // streaming prefetch pointers for x(t+1): k<FEAT -> nf row, k==127 -> tgt
        const float* px[2][2];
        int pxs[2][2];
#pragma unroll
        for (int rr = 0; rr < 2; ++rr) {
            const long rowg = b0 + wave * 2 + rr;
#pragma unroll
            for (int h = 0; h < 2; ++h) {
                const int k = lane + 64 * h;
                if (k < FEAT) { px[rr][h] = nf + (rowg * NSTEP + 1) * FEAT + k; pxs[rr][h] = FEAT; }
                else          { px[rr][h] = tgt + rowg * NSTEP;                 pxs[rr][h] = 1; }
            }
        }

        // stepping h0g store pointer: lane owns rows quad*4+r, unit u
        f16* hp = h0g + (long)(b0 + quad * 4) * NSTEP * 128 + u;

        f32x4 c0 = {0.f, 0.f, 0.f, 0.f};

        // stage x(0)
#pragma unroll
        for (int rr = 0; rr < 2; ++rr) {
            const int row = wave * 2 + rr;
            const long gbt = (long)(b0 + row) * NSTEP;
#pragma unroll
            for (int h = 0; h < 2; ++h) {
                const int k = lane + 64 * h;
                bufA[0][row][k] = (f16)((k < FEAT) ? nf[gbt * FEAT + k] : 0.0f);
            }
        }
        sync_lds();

        for (int t = 0; t < NSTEP; ++t) {
            const int pa = t & 1, wb = pa ^ 1;

            float xnv[2][2] = {{0.f, 0.f}, {0.f, 0.f}};
            if (t + 1 < NSTEP) {
#pragma unroll
                for (int rr = 0; rr < 2; ++rr)
#pragma unroll
                    for (int h = 0; h < 2; ++h)
                        xnv[rr][h] = *px[rr][h];
            }

            f16x8 ax[4], ah[4];
#pragma unroll
            for (int ks = 0; ks < 4; ++ks) {
                ax[ks] = *(const f16x8*)&bufA[pa][col][ks * 32 + quad * 8];
                ah[ks] = *(const f16x8*)&bufB[pa][col][ks * 32 + quad * 8];
            }

            // C-operand init: bias for x-chain, zero for h-chain (loop-invariant)
            f32x4 accx[4], acch[4];
#pragma unroll
            for (int g = 0; g < 4; ++g) {
                accx[g] = __builtin_amdgcn_mfma_f32_16x16x32_f16(ax[0], wih0[g][0], bv0[g], 0, 0, 0);
                acch[g] = __builtin_amdgcn_mfma_f32_16x16x32_f16(ah[0], whh0[g][0], zz, 0, 0, 0);
            }
#pragma unroll
            for (int ks = 1; ks < 4; ++ks)
#pragma unroll
                for (int g = 0; g < 4; ++g) {
                    accx[g] = __builtin_amdgcn_mfma_f32_16x16x32_f16(ax[ks], wih0[g][ks], accx[g], 0, 0, 0);
                    acch[g] = __builtin_amdgcn_mfma_f32_16x16x32_f16(ah[ks], whh0[g][ks], acch[g], 0, 0, 0);
                }

            float h0n[4];
#pragma unroll
            for (int r = 0; r < 4; ++r) {
                const float ig = sigf(accx[0][r] + acch[0][r]);
                const float fg = sigf(accx[1][r] + acch[1][r]);
                const float gg = tanh_(accx[2][r] + acch[2][r]);
                const float og = sigf(accx[3][r] + acch[3][r]);
                const float cn = fg * c0[r] + ig * gg;
                c0[r] = cn;
                h0n[r] = og * tanh_(cn);
            }
#pragma unroll
            for (int r = 0; r < 4; ++r) {
                bufB[wb][quad * 4 + r][u] = (f16)h0n[r];
                hp[r * (NSTEP * 128)] = (f16)h0n[r];   // store left in flight
            }
            hp += 128;

            if (t + 1 < NSTEP) {
#pragma unroll
                for (int rr = 0; rr < 2; ++rr)
#pragma unroll
                    for (int h = 0; h < 2; ++h) {
                        bufA[wb][wave * 2 + rr][lane + 64 * h] = (f16)xnv[rr][h];
                        px[rr][h] += pxs[rr][h];
                    }
            }
            sync_lds();
        }
    }

    // phase boundary: full drain so this block's h0g stores are visible to all
    // of its waves (block-local dependency only — no grid sync needed)
    __syncthreads();
    for (int i = tid; i < 2 * 16 * 152; i += NTHREADS)
        (&bufA[0][0][0])[i] = (f16)0.0f;           // bufA becomes h1 state
    __syncthreads();

    // ================= phase 1: layer 1 + output =============================
    {
        f32x4 bv1[4];
#pragma unroll
        for (int g = 0; g < 4; ++g) {
            const float b = b_ih1[g * 128 + u] + b_hh1[g * 128 + u];
            bv1[g] = (f32x4){b, b, b, b};
        }
        const float wo_u = w_out[u];
        const float bout = b_out[0];

        f16x8 wih1[4][4], whh1[4][4];
#pragma unroll
        for (int g = 0; g < 4; ++g)
#pragma unroll
            for (int ks = 0; ks < 4; ++ks) {
                wih1[g][ks] = load_wfrag(w_ih1, g * 128 + u, ks * 32 + quad * 8);
                whh1[g][ks] = load_wfrag(w_hh1, g * 128 + u, ks * 32 + quad * 8);
                PIN(wih1[g][ks]);
                PIN(whh1[g][ks]);
            }

        f32x4 c1 = {0.f, 0.f, 0.f, 0.f};

        // input A-fragments straight from h0g (block-local, L2-resident):
        // lane reads h0g[row=b0+col][t][ks*32+quad*8 .. +7], 16B aligned
        const f16* hrow = h0g + (long)(b0 + col) * NSTEP * 128 + quad * 8;
        f16x8 nx[4];
#pragma unroll
        for (int ks = 0; ks < 4; ++ks)
            nx[ks] = *(const f16x8*)(hrow + ks * 32);
        const f16* hnext = hrow + 128;             // t+1 prefetch pointer

        for (int t = 0; t < NSTEP; ++t) {
            const int pa = t & 1, wb = pa ^ 1;

            f16x8 ahv[4];
#pragma unroll
            for (int ks = 0; ks < 4; ++ks)
                ahv[ks] = *(const f16x8*)&bufA[pa][col][ks * 32 + quad * 8];

            f32x4 accx[4], acch[4];
#pragma unroll
            for (int g = 0; g < 4; ++g) {
                accx[g] = __builtin_amdgcn_mfma_f32_16x16x32_f16(nx[0], wih1[g][0], bv1[g], 0, 0, 0);
                acch[g] = __builtin_amdgcn_mfma_f32_16x16x32_f16(ahv[0], whh1[g][0], zz, 0, 0, 0);
            }
#pragma unroll
            for (int ks = 1; ks < 4; ++ks)
#pragma unroll
                for (int g = 0; g < 4; ++g) {
                    accx[g] = __builtin_amdgcn_mfma_f32_16x16x32_f16(nx[ks], wih1[g][ks], accx[g], 0, 0, 0);
                    acch[g] = __builtin_amdgcn_mfma_f32_16x16x32_f16(ahv[ks], whh1[g][ks], acch[g], 0, 0, 0);
                }

            // prefetch input frags for t+1 (registers, no LDS round trip)
            if (t + 1 < NSTEP) {
#pragma unroll
                for (int ks = 0; ks < 4; ++ks)
                    nx[ks] = *(const f16x8*)(hnext + ks * 32);
                hnext += 128;
            }

            float h1n[4];
#pragma unroll
            for (int r = 0; r < 4; ++r) {
                const float ig = sigf(accx[0][r] + acch[0][r]);
                const float fg = sigf(accx[1][r] + acch[1][r]);
                const float gg = tanh_(accx[2][r] + acch[2][r]);
                const float og = sigf(accx[3][r] + acch[3][r]);
                const float cn = fg * c1[r] + ig * gg;
                c1[r] = cn;
                h1n[r] = og * tanh_(cn);
            }
#pragma unroll
            for (int r = 0; r < 4; ++r)
                bufA[wb][quad * 4 + r][u] = (f16)h1n[r];

            // output partial: DPP row-sum over col (VALU only, result at col==15)
            float ps[4];
#pragma unroll
            for (int r = 0; r < 4; ++r) ps[r] = row16_sum(h1n[r] * wo_u);
            if (col == 15) {
#pragma unroll
                for (int r = 0; r < 4; ++r) outp[pa][wave][quad * 4 + r] = ps[r];
            }

            sync_lds();

            if (tid < 16) {
                float s = bout;
#pragma unroll
                for (int w = 0; w < 8; ++w) s += outp[pa][w][tid];
                out[(long)(b0 + tid) * NSTEP + t] = sigf(s);
            }
        }
    }
}

// ---------------- Fallback path (prep + single-kernel, known-passing) --------
__global__ void prep_weights(const float* __restrict__ w_ih0,
                             const float* __restrict__ w_hh0,
                             const float* __restrict__ w_ih1,
                             const float* __restrict__ w_hh1,
                             f16* __restrict__ ws16)
{
    int idx = blockIdx.x * blockDim.x + threadIdx.x;  // 0 .. 262143
    int j    = idx & 7;
    int lane = (idx >> 3) & 63;
    int ks   = (idx >> 9) & 3;
    int gate = (idx >> 11) & 3;
    int wave = (idx >> 13) & 7;
    int sel  = (idx >> 16) & 3;
    int n = gate * 128 + wave * 16 + (lane & 15);
    int k = ks * 32 + (lane >> 4) * 8 + j;
    const float* W = (sel == 0) ? w_ih0 : (sel == 1) ? w_hh0 : (sel == 2) ? w_ih1 : w_hh1;
    ws16[idx] = (f16)W[n * 128 + k];
}

__global__ __launch_bounds__(NTHREADS, 2) void lstm_fb(
    const float* __restrict__ nf,   const float* __restrict__ tgt,
    const float* __restrict__ b_ih0, const float* __restrict__ b_hh0,
    const float* __restrict__ b_ih1, const float* __restrict__ b_hh1,
    const float* __restrict__ w_out, const float* __restrict__ b_out,
    const f16* __restrict__ wfrag,  float* __restrict__ out)
{
    __shared__ f16 xs[2][16][152];
    __shared__ f16 h0s[2][16][152];
    __shared__ f16 h1s[2][16][152];
    __shared__ float outp[8][16];

    const int tid  = threadIdx.x;
    const int wave = tid >> 6;
    const int lane = tid & 63;
    const int col  = lane & 15;
    const int quad = lane >> 4;
    const int b0   = blockIdx.x * BLK_B;
    const int u    = wave * 16 + col;

    for (int i = tid; i < 2 * 16 * 152; i += NTHREADS) {
        (&h0s[0][0][0])[i] = (f16)0.0f;
        (&h1s[0][0][0])[i] = (f16)0.0f;
    }
    float bias0[4], bias1[4];
#pragma unroll
    for (int g = 0; g < 4; ++g) {
        bias0[g] = b_ih0[g * 128 + u] + b_hh0[g * 128 + u];
        bias1[g] = b_ih1[g * 128 + u] + b_hh1[g * 128 + u];
    }
    const float wo_u = w_out[u];
    const float bout = b_out[0];
    const f16x8* wf = (const f16x8*)wfrag;

    f32x4 c0 = {0.f, 0.f, 0.f, 0.f};
    f32x4 c1 = {0.f, 0.f, 0.f, 0.f};

#pragma unroll
    for (int rr = 0; rr < 2; ++rr) {
        const int row = wave * 2 + rr;
        const long gbt = (long)(b0 + row) * NSTEP;
#pragma unroll
        for (int h = 0; h < 2; ++h) {
            const int k = lane + 64 * h;
            xs[0][row][k] = (f16)((k < FEAT) ? nf[gbt * FEAT + k] : 0.0f);
        }
    }
    __syncthreads();

    for (int t = 0; t < NSTEP; ++t) {
        const int pa = t & 1, wb = pa ^ 1;
        float xnv[2][2];
#pragma unroll
        for (int rr = 0; rr < 2; ++rr) {
            const int row = wave * 2 + rr;
#pragma unroll
            for (int h = 0; h < 2; ++h) {
                const int k = lane + 64 * h;
                float v = 0.0f;
                if (t + 1 < NSTEP) {
                    const long gbt = (long)(b0 + row) * NSTEP + (t + 1);
                    v = (k < FEAT) ? nf[gbt * FEAT + k] : tgt[(long)(b0 + row) * NSTEP + t];
                }
                xnv[rr][h] = v;
            }
        }
        f32x4 acc[4];
#pragma unroll
        for (int g = 0; g < 4; ++g) acc[g] = (f32x4){bias0[g], bias0[g], bias0[g], bias0[g]};
#pragma unroll
        for (int ks = 0; ks < 4; ++ks) {
            f16x8 a = *(const f16x8*)&xs[pa][col][ks * 32 + quad * 8];
#pragma unroll
            for (int g = 0; g < 4; ++g) {
                f16x8 b = wf[((wave * 4 + g) * 4 + ks) * 64 + lane];
                acc[g] = __builtin_amdgcn_mfma_f32_16x16x32_f16(a, b, acc[g], 0, 0, 0);
            }
        }
#pragma unroll
        for (int ks = 0; ks < 4; ++ks) {
            f16x8 a = *(const f16x8*)&h0s[pa][col][ks * 32 + quad * 8];
#pragma unroll
            for (int g = 0; g < 4; ++g) {
                f16x8 b = wf[1 * 8192 + ((wave * 4 + g) * 4 + ks) * 64 + lane];
                acc[g] = __builtin_amdgcn_mfma_f32_16x16x32_f16(a, b, acc[g], 0, 0, 0);
            }
        }
        float h0n[4];
#pragma unroll
        for (int r = 0; r < 4; ++r) {
            const float ig = sigf(acc[0][r]);
            const float fg = sigf(acc[1][r]);
            const float gg = tanh_(acc[2][r]);
            const float og = sigf(acc[3][r]);
            const float cn = fg * c0[r] + ig * gg;
            c0[r] = cn;
            h0n[r] = og * tanh_(cn);
        }
#pragma unroll
        for (int r = 0; r < 4; ++r) h0s[wb][quad * 4 + r][u] = (f16)h0n[r];
        __syncthreads();

#pragma unroll
        for (int g = 0; g < 4; ++g) acc[g] = (f32x4){bias1[g], bias1[g], bias1[g], bias1[g]};
#pragma unroll
        for (int ks = 0; ks < 4; ++ks) {
            f16x8 a = *(const f16x8*)&h0s[wb][col][ks * 32 + quad * 8];
#pragma unroll
            for (int g = 0; g < 4; ++g) {
                f16x8 b = wf[2 * 8192 + ((wave * 4 + g) * 4 + ks) * 64 + lane];
                acc[g] = __builtin_amdgcn_mfma_f32_16x16x32_f16(a, b, acc[g], 0, 0, 0);
            }
        }
#pragma unroll
        for (int ks = 0; ks < 4; ++ks) {
            f16x8 a = *(const f16x8*)&h1s[pa][col][ks * 32 + quad * 8];
#pragma unroll
            for (int g = 0; g < 4; ++g) {
                f16x8 b = wf[3 * 8192 + ((wave * 4 + g) * 4 + ks) * 64 + lane];
                acc[g] = __builtin_amdgcn_mfma_f32_16x16x32_f16(a, b, acc[g], 0, 0, 0);
            }
        }
        float h1n[4];
#pragma unroll
        for (int r = 0; r < 4; ++r) {
            const float ig = sigf(acc[0][r]);
            const float fg = sigf(acc[1][r]);
            const float gg = tanh_(acc[2][r]);
            const float og = sigf(acc[3][r]);
            const float cn = fg * c1[r] + ig * gg;
            c1[r] = cn;
            h1n[r] = og * tanh_(cn);
        }
#pragma unroll
        for (int r = 0; r < 4; ++r) h1s[wb][quad * 4 + r][u] = (f16)h1n[r];
#pragma unroll
        for (int rr = 0; rr < 2; ++rr) {
            const int row = wave * 2 + rr;
#pragma unroll
            for (int h = 0; h < 2; ++h) xs[wb][row][lane + 64 * h] = (f16)xnv[rr][h];
        }
        float ps[4];
#pragma unroll
        for (int r = 0; r < 4; ++r) ps[r] = h1n[r] * wo_u;
#pragma unroll
        for (int m = 1; m < 16; m <<= 1) {
#pragma unroll
            for (int r = 0; r < 4; ++r) ps[r] += __shfl_xor(ps[r], m, 64);
        }
        if (col == 0) {
#pragma unroll
            for (int r = 0; r < 4; ++r) outp[wave][quad * 4 + r] = ps[r];
        }
        __syncthreads();
        if (tid < 16) {
            float s = bout;
#pragma unroll
            for (int w = 0; w < 8; ++w) s += outp[w][tid];
            out[(long)(b0 + tid) * NSTEP + t] = sigf(s);
        }
    }
}

extern "C" void kernel_launch(void* const* d_in, const int* in_sizes, int n_in,
                              void* d_out, int out_size, void* d_ws, size_t ws_size,
                              hipStream_t stream)
{
    const float* nf    = (const float*)d_in[0];
    const float* tgt   = (const float*)d_in[1];
    const float* w_ih0 = (const float*)d_in[2];
    const float* w_hh0 = (const float*)d_in[3];
    const float* b_ih0 = (const float*)d_in[4];
    const float* b_hh0 = (const float*)d_in[5];
    const float* w_ih1 = (const float*)d_in[6];
    const float* w_hh1 = (const float*)d_in[7];
    const float* b_ih1 = (const float*)d_in[8];
    const float* b_hh1 = (const float*)d_in[9];
    const float* w_out = (const float*)d_in[10];
    const float* b_out = (const float*)d_in[11];

    float* out = (float*)d_out;

    const size_t need = (size_t)4096 * 128 * 128 * 2;   // h0g f16 = 128 MB
    if (ws_size >= need) {
        f16* h0g = (f16*)d_ws;
        lstm_fused<<<NBLOCK, NTHREADS, 0, stream>>>(
            nf, tgt, w_ih0, w_hh0, b_ih0, b_hh0,
            w_ih1, w_hh1, b_ih1, b_hh1, w_out, b_out, h0g, out);
    } else {
        f16* ws16 = (f16*)d_ws;                         // 512 KB fragments
        prep_weights<<<1024, 256, 0, stream>>>(w_ih0, w_hh0, w_ih1, w_hh1, ws16);
        lstm_fb<<<NBLOCK, NTHREADS, 0, stream>>>(nf, tgt, b_ih0, b_hh0, b_ih1, b_hh1,
                                                 w_out, b_out, ws16, out);
    }
}

// Round 5
// 781.040 us; speedup vs baseline: 1.0946x; 1.0114x over previous
//
#include <hip/hip_runtime.h>
#include <math.h>

typedef _Float16 f16;
typedef _Float16 f16x8 __attribute__((ext_vector_type(8)));
typedef float f32x4 __attribute__((ext_vector_type(4)));

#define NSTEP 128
#define FEAT  127
#define BLK_B 16
#define NBLOCK 256
#define NTHREADS 512

__device__ __forceinline__ float sigf(float x) { return 1.0f / (1.0f + __expf(-x)); }
__device__ __forceinline__ float tanh_(float x) { return 1.0f - 2.0f / (1.0f + __expf(2.0f * x)); }

// Barrier that only guarantees LDS visibility: no vmcnt(0) drain, so global
// stores (h0g/out) and prefetch loads stay in flight across steps.
__device__ __forceinline__ void sync_lds() {
    asm volatile("s_waitcnt lgkmcnt(0)" ::: "memory");
    __builtin_amdgcn_s_barrier();
    asm volatile("" ::: "memory");
}

#define PIN(v) asm volatile("" : "+v"(v))

// Load one MFMA B-fragment directly from the f32 weight matrix.
// Lane holds W[n][k..k+7] as f16x8 (same RTE conversion as the old prep kernel).
__device__ __forceinline__ f16x8 load_wfrag(const float* __restrict__ W, int n, int k) {
    const float* p = W + n * 128 + k;
    f16x8 r;
#pragma unroll
    for (int j = 0; j < 8; ++j) r[j] = (f16)p[j];
    return r;
}

// Sum over the 16-lane DPP row (our `col` dimension) via row_shr cascade.
// DPP ctrl must be a literal constant -> hand-unrolled. bound_ctrl=1 reads 0
// for shifted-in lanes. Result valid at col==15 of each 16-lane row.
__device__ __forceinline__ float row16_sum(float v) {
    int t;
    t = __builtin_amdgcn_update_dpp(0, __float_as_int(v), 0x118, 0xf, 0xf, true); // row_shr:8
    v += __int_as_float(t);
    t = __builtin_amdgcn_update_dpp(0, __float_as_int(v), 0x114, 0xf, 0xf, true); // row_shr:4
    v += __int_as_float(t);
    t = __builtin_amdgcn_update_dpp(0, __float_as_int(v), 0x112, 0xf, 0xf, true); // row_shr:2
    v += __int_as_float(t);
    t = __builtin_amdgcn_update_dpp(0, __float_as_int(v), 0x111, 0xf, 0xf, true); // row_shr:1
    v += __int_as_float(t);
    return v;
}

// ---------------- Fused kernel: layer 0 then layer 1, block-local ------------
__global__ __launch_bounds__(NTHREADS, 2) void lstm_fused(
    const float* __restrict__ nf,    const float* __restrict__ tgt,
    const float* __restrict__ w_ih0, const float* __restrict__ w_hh0,
    const float* __restrict__ b_ih0, const float* __restrict__ b_hh0,
    const float* __restrict__ w_ih1, const float* __restrict__ w_hh1,
    const float* __restrict__ b_ih1, const float* __restrict__ b_hh1,
    const float* __restrict__ w_out, const float* __restrict__ b_out,
    f16* __restrict__ h0g, float* __restrict__ out)
{
    __shared__ __align__(16) f16 bufA[2][16][152];   // phase0: xs   phase1: h1s
    __shared__ __align__(16) f16 bufB[2][16][152];   // phase0: h0s
    __shared__ float outp[2][8][16];

    const int tid  = threadIdx.x;
    const int wave = tid >> 6;
    const int lane = tid & 63;
    const int col  = lane & 15;
    const int quad = lane >> 4;
    const int b0   = blockIdx.x * BLK_B;
    const int u    = wave * 16 + col;
    const f32x4 zz = {0.f, 0.f, 0.f, 0.f};

    // ================= phase 0: layer 0, h0 sequence -> h0g ==================
    {
        for (int i = tid; i < 2 * 16 * 152; i += NTHREADS)
            (&bufB[0][0][0])[i] = (f16)0.0f;

        f32x4 bv0[4];
#pragma unroll
        for (int g = 0; g < 4; ++g) {
            const float b = b_ih0[g * 128 + u] + b_hh0[g * 128 + u];
            bv0[g] = (f32x4){b, b, b, b};
        }

        // weight fragments straight from global f32 (no prep kernel)
        f16x8 wih0[4][4], whh0[4][4];
#pragma unroll
        for (int g = 0; g < 4; ++g)
#pragma unroll
            for (int ks = 0; ks < 4; ++ks) {
                wih0[g][ks] = load_wfrag(w_ih0, g * 128 + u, ks * 32 + quad * 8);
                whh0[g][ks] = load_wfrag(w_hh0, g * 128 + u, ks * 32 + quad * 8);
                PIN(wih0[g][ks]);
                PIN(whh0[g][ks]);
            }

        // streaming prefetch pointers, pointing at x(2) elements:
        // k<FEAT -> nf row, k==127 -> tgt (x(t)'s cond = tgt[t-1])
        const float* px[2][2];
        int pxs[2][2];
#pragma unroll
        for (int rr = 0; rr < 2; ++rr) {
            const long rowg = b0 + wave * 2 + rr;
#pragma unroll
            for (int h = 0; h < 2; ++h) {
                const int k = lane + 64 * h;
                if (k < FEAT) { px[rr][h] = nf + (rowg * NSTEP + 2) * FEAT + k; pxs[rr][h] = FEAT; }
                else          { px[rr][h] = tgt + rowg * NSTEP + 1;             pxs[rr][h] = 1; }
            }
        }

        // stepping h0g store pointer: lane owns rows quad*4+r, unit u
        f16* hp = h0g + (long)(b0 + quad * 4) * NSTEP * 128 + u;

        f32x4 c0 = {0.f, 0.f, 0.f, 0.f};

        // stage x(0) directly to LDS
#pragma unroll
        for (int rr = 0; rr < 2; ++rr) {
            const int row = wave * 2 + rr;
            const long gbt = (long)(b0 + row) * NSTEP;
#pragma unroll
            for (int h = 0; h < 2; ++h) {
                const int k = lane + 64 * h;
                bufA[0][row][k] = (f16)((k < FEAT) ? nf[gbt * FEAT + k] : 0.0f);
            }
        }

        // prologue prefetch: xb1 <- x(1)
        float xb0[2][2], xb1[2][2];
#pragma unroll
        for (int rr = 0; rr < 2; ++rr) {
            const long rowg = b0 + wave * 2 + rr;
#pragma unroll
            for (int h = 0; h < 2; ++h) {
                const int k = lane + 64 * h;
                xb1[rr][h] = (k < FEAT) ? nf[(rowg * NSTEP + 1) * FEAT + k]
                                        : tgt[rowg * NSTEP];
            }
        }
        sync_lds();

        // one LSTM-0 step: consumes xs[pa]; issues loads for x(t+2) into xIssue;
        // writes x(t+1) (already resident in xWrite) to xs[pa^1].
        auto step0 = [&](int t, int pa, float (&xIssue)[2][2], float (&xWrite)[2][2]) {
            const int wb = pa ^ 1;

            // issue 2-step-ahead loads (full-step slack to their vmcnt wait)
            if (t + 2 < NSTEP) {
#pragma unroll
                for (int rr = 0; rr < 2; ++rr)
#pragma unroll
                    for (int h = 0; h < 2; ++h) {
                        xIssue[rr][h] = *px[rr][h];
                        px[rr][h] += pxs[rr][h];
                    }
            }

            f16x8 ax[4], ah[4];
#pragma unroll
            for (int ks = 0; ks < 4; ++ks) {
                ax[ks] = *(const f16x8*)&bufA[pa][col][ks * 32 + quad * 8];
                ah[ks] = *(const f16x8*)&bufB[pa][col][ks * 32 + quad * 8];
            }

            f32x4 accx[4], acch[4];
#pragma unroll
            for (int g = 0; g < 4; ++g) {
                accx[g] = __builtin_amdgcn_mfma_f32_16x16x32_f16(ax[0], wih0[g][0], bv0[g], 0, 0, 0);
                acch[g] = __builtin_amdgcn_mfma_f32_16x16x32_f16(ah[0], whh0[g][0], zz, 0, 0, 0);
            }
#pragma unroll
            for (int ks = 1; ks < 4; ++ks)
#pragma unroll
                for (int g = 0; g < 4; ++g) {
                    accx[g] = __builtin_amdgcn_mfma_f32_16x16x32_f16(ax[ks], wih0[g][ks], accx[g], 0, 0, 0);
                    acch[g] = __builtin_amdgcn_mfma_f32_16x16x32_f16(ah[ks], whh0[g][ks], acch[g], 0, 0, 0);
                }

            float h0n[4];
#pragma unroll
            for (int r = 0; r < 4; ++r) {
                const float ig = sigf(accx[0][r] + acch[0][r]);
                const float fg = sigf(accx[1][r] + acch[1][r]);
                const float gg = tanh_(accx[2][r] + acch[2][r]);
                const float og = sigf(accx[3][r] + acch[3][r]);
                const float cn = fg * c0[r] + ig * gg;
                c0[r] = cn;
                h0n[r] = og * tanh_(cn);
            }
#pragma unroll
            for (int r = 0; r < 4; ++r) {
                bufB[wb][quad * 4 + r][u] = (f16)h0n[r];
                hp[r * (NSTEP * 128)] = (f16)h0n[r];   // store left in flight
            }
            hp += 128;

            // stage x(t+1) (loaded two steps ago — definitely arrived)
            if (t + 1 < NSTEP) {
#pragma unroll
                for (int rr = 0; rr < 2; ++rr)
#pragma unroll
                    for (int h = 0; h < 2; ++h)
                        bufA[wb][wave * 2 + rr][lane + 64 * h] = (f16)xWrite[rr][h];
            }
            sync_lds();
        };

        for (int t2 = 0; t2 < NSTEP; t2 += 2) {
            step0(t2,     0, xb0, xb1);   // consume x(t2),   write x(t2+1)=xb1, issue x(t2+2)->xb0
            step0(t2 + 1, 1, xb1, xb0);   // consume x(t2+1), write x(t2+2)=xb0, issue x(t2+3)->xb1
        }
    }

    // phase boundary: full drain so this block's h0g stores are visible to all
    // of its waves (block-local dependency only — no grid sync needed)
    __syncthreads();
    for (int i = tid; i < 2 * 16 * 152; i += NTHREADS)
        (&bufA[0][0][0])[i] = (f16)0.0f;           // bufA becomes h1 state
    __syncthreads();

    // ================= phase 1: layer 1 + output =============================
    {
        f32x4 bv1[4];
#pragma unroll
        for (int g = 0; g < 4; ++g) {
            const float b = b_ih1[g * 128 + u] + b_hh1[g * 128 + u];
            bv1[g] = (f32x4){b, b, b, b};
        }
        const float wo_u = w_out[u];
        const float bout = b_out[0];

        f16x8 wih1[4][4], whh1[4][4];
#pragma unroll
        for (int g = 0; g < 4; ++g)
#pragma unroll
            for (int ks = 0; ks < 4; ++ks) {
                wih1[g][ks] = load_wfrag(w_ih1, g * 128 + u, ks * 32 + quad * 8);
                whh1[g][ks] = load_wfrag(w_hh1, g * 128 + u, ks * 32 + quad * 8);
                PIN(wih1[g][ks]);
                PIN(whh1[g][ks]);
            }

        f32x4 c1 = {0.f, 0.f, 0.f, 0.f};

        // input A-fragments straight from h0g (block-local, L3-resident):
        // lane reads h0g[row=b0+col][t][ks*32+quad*8 .. +7], 16B aligned.
        // 2-deep parity prefetch: nxA holds even-t frags, nxB odd-t frags.
        const f16* hrow = h0g + (long)(b0 + col) * NSTEP * 128 + quad * 8;
        f16x8 nxA[4], nxB[4];
#pragma unroll
        for (int ks = 0; ks < 4; ++ks)
            nxA[ks] = *(const f16x8*)(hrow + ks * 32);            // t=0
#pragma unroll
        for (int ks = 0; ks < 4; ++ks)
            nxB[ks] = *(const f16x8*)(hrow + 128 + ks * 32);      // t=1
        const f16* hnext = hrow + 256;                            // t=2 onward

        auto step1 = [&](int t, int pa, f16x8 (&nxUse)[4]) {
            const int wb = pa ^ 1;

            f16x8 ahv[4];
#pragma unroll
            for (int ks = 0; ks < 4; ++ks)
                ahv[ks] = *(const f16x8*)&bufA[pa][col][ks * 32 + quad * 8];

            f32x4 accx[4], acch[4];
#pragma unroll
            for (int g = 0; g < 4; ++g) {
                accx[g] = __builtin_amdgcn_mfma_f32_16x16x32_f16(nxUse[0], wih1[g][0], bv1[g], 0, 0, 0);
                acch[g] = __builtin_amdgcn_mfma_f32_16x16x32_f16(ahv[0], whh1[g][0], zz, 0, 0, 0);
            }
#pragma unroll
            for (int ks = 1; ks < 4; ++ks)
#pragma unroll
                for (int g = 0; g < 4; ++g) {
                    accx[g] = __builtin_amdgcn_mfma_f32_16x16x32_f16(nxUse[ks], wih1[g][ks], accx[g], 0, 0, 0);
                    acch[g] = __builtin_amdgcn_mfma_f32_16x16x32_f16(ahv[ks], whh1[g][ks], acch[g], 0, 0, 0);
                }

            // re-issue this parity buffer for t+2 (full-step slack to next use)
            if (t + 2 < NSTEP) {
#pragma unroll
                for (int ks = 0; ks < 4; ++ks)
                    nxUse[ks] = *(const f16x8*)(hnext + ks * 32);
                hnext += 128;
            }

            float h1n[4];
#pragma unroll
            for (int r = 0; r < 4; ++r) {
                const float ig = sigf(accx[0][r] + acch[0][r]);
                const float fg = sigf(accx[1][r] + acch[1][r]);
                const float gg = tanh_(accx[2][r] + acch[2][r]);
                const float og = sigf(accx[3][r] + acch[3][r]);
                const float cn = fg * c1[r] + ig * gg;
                c1[r] = cn;
                h1n[r] = og * tanh_(cn);
            }
#pragma unroll
            for (int r = 0; r < 4; ++r)
                bufA[wb][quad * 4 + r][u] = (f16)h1n[r];

            // output partial: DPP row-sum over col (VALU only, result at col==15)
            float ps[4];
#pragma unroll
            for (int r = 0; r < 4; ++r) ps[r] = row16_sum(h1n[r] * wo_u);
            if (col == 15) {
#pragma unroll
                for (int r = 0; r < 4; ++r) outp[pa][wave][quad * 4 + r] = ps[r];
            }

            sync_lds();

            if (tid < 16) {
                float s = bout;
#pragma unroll
                for (int w = 0; w < 8; ++w) s += outp[pa][w][tid];
                out[(long)(b0 + tid) * NSTEP + t] = sigf(s);
            }
        };

        for (int t2 = 0; t2 < NSTEP; t2 += 2) {
            step1(t2,     0, nxA);
            step1(t2 + 1, 1, nxB);
        }
    }
}

// ---------------- Fallback path (prep + single-kernel, known-passing) --------
__global__ void prep_weights(const float* __restrict__ w_ih0,
                             const float* __restrict__ w_hh0,
                             const float* __restrict__ w_ih1,
                             const float* __restrict__ w_hh1,
                             f16* __restrict__ ws16)
{
    int idx = blockIdx.x * blockDim.x + threadIdx.x;  // 0 .. 262143
    int j    = idx & 7;
    int lane = (idx >> 3) & 63;
    int ks   = (idx >> 9) & 3;
    int gate = (idx >> 11) & 3;
    int wave = (idx >> 13) & 7;
    int sel  = (idx >> 16) & 3;
    int n = gate * 128 + wave * 16 + (lane & 15);
    int k = ks * 32 + (lane >> 4) * 8 + j;
    const float* W = (sel == 0) ? w_ih0 : (sel == 1) ? w_hh0 : (sel == 2) ? w_ih1 : w_hh1;
    ws16[idx] = (f16)W[n * 128 + k];
}

__global__ __launch_bounds__(NTHREADS, 2) void lstm_fb(
    const float* __restrict__ nf,   const float* __restrict__ tgt,
    const float* __restrict__ b_ih0, const float* __restrict__ b_hh0,
    const float* __restrict__ b_ih1, const float* __restrict__ b_hh1,
    const float* __restrict__ w_out, const float* __restrict__ b_out,
    const f16* __restrict__ wfrag,  float* __restrict__ out)
{
    __shared__ f16 xs[2][16][152];
    __shared__ f16 h0s[2][16][152];
    __shared__ f16 h1s[2][16][152];
    __shared__ float outp[8][16];

    const int tid  = threadIdx.x;
    const int wave = tid >> 6;
    const int lane = tid & 63;
    const int col  = lane & 15;
    const int quad = lane >> 4;
    const int b0   = blockIdx.x * BLK_B;
    const int u    = wave * 16 + col;

    for (int i = tid; i < 2 * 16 * 152; i += NTHREADS) {
        (&h0s[0][0][0])[i] = (f16)0.0f;
        (&h1s[0][0][0])[i] = (f16)0.0f;
    }
    float bias0[4], bias1[4];
#pragma unroll
    for (int g = 0; g < 4; ++g) {
        bias0[g] = b_ih0[g * 128 + u] + b_hh0[g * 128 + u];
        bias1[g] = b_ih1[g * 128 + u] + b_hh1[g * 128 + u];
    }
    const float wo_u = w_out[u];
    const float bout = b_out[0];
    const f16x8* wf = (const f16x8*)wfrag;

    f32x4 c0 = {0.f, 0.f, 0.f, 0.f};
    f32x4 c1 = {0.f, 0.f, 0.f, 0.f};

#pragma unroll
    for (int rr = 0; rr < 2; ++rr) {
        const int row = wave * 2 + rr;
        const long gbt = (long)(b0 + row) * NSTEP;
#pragma unroll
        for (int h = 0; h < 2; ++h) {
            const int k = lane + 64 * h;
            xs[0][row][k] = (f16)((k < FEAT) ? nf[gbt * FEAT + k] : 0.0f);
        }
    }
    __syncthreads();

    for (int t = 0; t < NSTEP; ++t) {
        const int pa = t & 1, wb = pa ^ 1;
        float xnv[2][2];
#pragma unroll
        for (int rr = 0; rr < 2; ++rr) {
            const int row = wave * 2 + rr;
#pragma unroll
            for (int h = 0; h < 2; ++h) {
                const int k = lane + 64 * h;
                float v = 0.0f;
                if (t + 1 < NSTEP) {
                    const long gbt = (long)(b0 + row) * NSTEP + (t + 1);
                    v = (k < FEAT) ? nf[gbt * FEAT + k] : tgt[(long)(b0 + row) * NSTEP + t];
                }
                xnv[rr][h] = v;
            }
        }
        f32x4 acc[4];
#pragma unroll
        for (int g = 0; g < 4; ++g) acc[g] = (f32x4){bias0[g], bias0[g], bias0[g], bias0[g]};
#pragma unroll
        for (int ks = 0; ks < 4; ++ks) {
            f16x8 a = *(const f16x8*)&xs[pa][col][ks * 32 + quad * 8];
#pragma unroll
            for (int g = 0; g < 4; ++g) {
                f16x8 b = wf[((wave * 4 + g) * 4 + ks) * 64 + lane];
                acc[g] = __builtin_amdgcn_mfma_f32_16x16x32_f16(a, b, acc[g], 0, 0, 0);
            }
        }
#pragma unroll
        for (int ks = 0; ks < 4; ++ks) {
            f16x8 a = *(const f16x8*)&h0s[pa][col][ks * 32 + quad * 8];
#pragma unroll
            for (int g = 0; g < 4; ++g) {
                f16x8 b = wf[1 * 8192 + ((wave * 4 + g) * 4 + ks) * 64 + lane];
                acc[g] = __builtin_amdgcn_mfma_f32_16x16x32_f16(a, b, acc[g], 0, 0, 0);
            }
        }
        float h0n[4];
#pragma unroll
        for (int r = 0; r < 4; ++r) {
            const float ig = sigf(acc[0][r]);
            const float fg = sigf(acc[1][r]);
            const float gg = tanh_(acc[2][r]);
            const float og = sigf(acc[3][r]);
            const float cn = fg * c0[r] + ig * gg;
            c0[r] = cn;
            h0n[r] = og * tanh_(cn);
        }
#pragma unroll
        for (int r = 0; r < 4; ++r) h0s[wb][quad * 4 + r][u] = (f16)h0n[r];
        __syncthreads();

#pragma unroll
        for (int g = 0; g < 4; ++g) acc[g] = (f32x4){bias1[g], bias1[g], bias1[g], bias1[g]};
#pragma unroll
        for (int ks = 0; ks < 4; ++ks) {
            f16x8 a = *(const f16x8*)&h0s[wb][col][ks * 32 + quad * 8];
#pragma unroll
            for (int g = 0; g < 4; ++g) {
                f16x8 b = wf[2 * 8192 + ((wave * 4 + g) * 4 + ks) * 64 + lane];
                acc[g] = __builtin_amdgcn_mfma_f32_16x16x32_f16(a, b, acc[g], 0, 0, 0);
            }
        }
#pragma unroll
        for (int ks = 0; ks < 4; ++ks) {
            f16x8 a = *(const f16x8*)&h1s[pa][col][ks * 32 + quad * 8];
#pragma unroll
            for (int g = 0; g < 4; ++g) {
                f16x8 b = wf[3 * 8192 + ((wave * 4 + g) * 4 + ks) * 64 + lane];
                acc[g] = __builtin_amdgcn_mfma_f32_16x16x32_f16(a, b, acc[g], 0, 0, 0);
            }
        }
        float h1n[4];
#pragma unroll
        for (int r = 0; r < 4; ++r) {
            const float ig = sigf(acc[0][r]);
            const float fg = sigf(acc[1][r]);
            const float gg = tanh_(acc[2][r]);
            const float og = sigf(acc[3][r]);
            const float cn = fg * c1[r] + ig * gg;
            c1[r] = cn;
            h1n[r] = og * tanh_(cn);
        }
#pragma unroll
        for (int r = 0; r < 4; ++r) h1s[wb][quad * 4 + r][u] = (f16)h1n[r];
#pragma unroll
        for (int rr = 0; rr < 2; ++rr) {
            const int row = wave * 2 + rr;
#pragma unroll
            for (int h = 0; h < 2; ++h) xs[wb][row][lane + 64 * h] = (f16)xnv[rr][h];
        }
        float ps[4];
#pragma unroll
        for (int r = 0; r < 4; ++r) ps[r] = h1n[r] * wo_u;
#pragma unroll
        for (int m = 1; m < 16; m <<= 1) {
#pragma unroll
            for (int r = 0; r < 4; ++r) ps[r] += __shfl_xor(ps[r], m, 64);
        }
        if (col == 0) {
#pragma unroll
            for (int r = 0; r < 4; ++r) outp[wave][quad * 4 + r] = ps[r];
        }
        __syncthreads();
        if (tid < 16) {
            float s = bout;
#pragma unroll
            for (int w = 0; w < 8; ++w) s += outp[w][tid];
            out[(long)(b0 + tid) * NSTEP + t] = sigf(s);
        }
    }
}

extern "C" void kernel_launch(void* const* d_in, const int* in_sizes, int n_in,
                              void* d_out, int out_size, void* d_ws, size_t ws_size,
                              hipStream_t stream)
{
    const float* nf    = (const float*)d_in[0];
    const float* tgt   = (const float*)d_in[1];
    const float* w_ih0 = (const float*)d_in[2];
    const float* w_hh0 = (const float*)d_in[3];
    const float* b_ih0 = (const float*)d_in[4];
    const float* b_hh0 = (const float*)d_in[5];
    const float* w_ih1 = (const float*)d_in[6];
    const float* w_hh1 = (const float*)d_in[7];
    const float* b_ih1 = (const float*)d_in[8];
    const float* b_hh1 = (const float*)d_in[9];
    const float* w_out = (const float*)d_in[10];
    const float* b_out = (const float*)d_in[11];

    float* out = (float*)d_out;

    const size_t need = (size_t)4096 * 128 * 128 * 2;   // h0g f16 = 128 MB
    if (ws_size >= need) {
        f16* h0g = (f16*)d_ws;
        lstm_fused<<<NBLOCK, NTHREADS, 0, stream>>>(
            nf, tgt, w_ih0, w_hh0, b_ih0, b_hh0,
            w_ih1, w_hh1, b_ih1, b_hh1, w_out, b_out, h0g, out);
    } else {
        f16* ws16 = (f16*)d_ws;                         // 512 KB fragments
        prep_weights<<<1024, 256, 0, stream>>>(w_ih0, w_hh0, w_ih1, w_hh1, ws16);
        lstm_fb<<<NBLOCK, NTHREADS, 0, stream>>>(nf, tgt, b_ih0, b_hh0, b_ih1, b_hh1,
                                                 w_out, b_out, ws16, out);
    }
}